// Round 13
// baseline (2011.047 us; speedup 1.0000x reference)
//
#include <hip/hip_runtime.h>
#include <hip/hip_fp16.h>

#define B_   16
#define L_   4096
#define DIN  64
#define H_   256
#define N_   32
#define NL_  4
#define DOUT 10
#define CH_  32
#define T_   128
#define NBLK 512

#define GAS const __attribute__((address_space(1)))
#define LAS __attribute__((address_space(3)))

typedef _Float16 half8 __attribute__((ext_vector_type(8)));
typedef _Float16 half4 __attribute__((ext_vector_type(4)));
typedef float f32x4 __attribute__((ext_vector_type(4)));

__device__ __forceinline__ float gelu_f(float v) {
    float t3  = v * v * v;
    float arg = 0.7978845608028654f * fmaf(0.044715f, t3, v);
    float e   = __expf(2.f * arg);
    float th  = 1.f - 2.f / (e + 1.f);
    return 0.5f * v * (1.f + th);
}

// all-resident grid barrier (grid=512=2/CU guaranteed by launch_bounds+LDS)
__device__ __forceinline__ void gbar(int* bar, int phase) {
    __syncthreads();
    if (threadIdx.x == 0) {
        int* cnt = bar + phase * 32;
        int* flg = bar + phase * 32 + 16;
        __threadfence();
        int v = __hip_atomic_fetch_add(cnt, 1, __ATOMIC_ACQ_REL, __HIP_MEMORY_SCOPE_AGENT);
        if (v == NBLK - 1) {
            __hip_atomic_store(flg, 1, __ATOMIC_RELEASE, __HIP_MEMORY_SCOPE_AGENT);
        } else {
            while (!__hip_atomic_load(flg, __ATOMIC_ACQUIRE, __HIP_MEMORY_SCOPE_AGENT))
                __builtin_amdgcn_s_sleep(2);
        }
        __threadfence();
    }
    __syncthreads();
}

// ---------------- table generation + weight prep: per (layer,h) block ----------------
__global__ __launch_bounds__(256) void gen_k(
    const float* __restrict__ log_dt, const float* __restrict__ log_A_real,
    const float* __restrict__ A_imag, const float* __restrict__ C_re, const float* __restrict__ C_im,
    const float* __restrict__ Dp,
    _Float16* __restrict__ Wv, _Float16* __restrict__ Vt, _Float16* __restrict__ G,
    float* __restrict__ wtr, float* __restrict__ wti,
    const float* __restrict__ outw, _Float16* __restrict__ w16,
    const float* __restrict__ dw, _Float16* __restrict__ dwp)
{
    __shared__ float sxr[N_], sxi[N_], scr[N_], sci[N_], skd[T_];
    int ih = blockIdx.x;
    int t  = threadIdx.x;
    {
        int base = ih * 512 + t;
        w16[base]       = (_Float16)outw[base];
        w16[base + 256] = (_Float16)outw[base + 256];
    }
    if (ih == 0) {
#pragma unroll
        for (int j = 0; j < 16; j++) {
            int idx = j * 256 + t;
            dwp[idx] = (idx < DOUT * H_) ? (_Float16)dw[idx] : (_Float16)0.f;
        }
    }
    if (t < N_) {
        int n = t;
        float dt  = expf(log_dt[ih]);
        float Are = -expf(log_A_real[ih * N_ + n]);
        float Aim = A_imag[ih * N_ + n];
        float xr = dt * Are, xi = dt * Aim;
        float ex = expf(xr), cy = cosf(xi), sy = sinf(xi);
        float sh = sinf(0.5f * xi);
        float em_re = expm1f(xr) * cy - 2.f * sh * sh;
        float em_im = ex * sy;
        float inv = 1.f / (Are * Are + Aim * Aim);
        float qr = (em_re * Are + em_im * Aim) * inv;
        float qi = (em_im * Are - em_re * Aim) * inv;
        float crv = C_re[ih * N_ + n], civ = C_im[ih * N_ + n];
        sxr[n] = xr; sxi[n] = xi;
        scr[n] = 2.f * (crv * qr - civ * qi);
        sci[n] = 2.f * (crv * qi + civ * qr);
        float txr = 128.f * xr, txi = 128.f * xi;
        float exT = expf(txr);
        wtr[ih * N_ + n] = exT * cosf(txi);
        wti[ih * N_ + n] = exT * sinf(txi);
    }
    __syncthreads();
    if (t <= T_) {
        int d = t;
        float fd = (float)d;
        float kd = 0.f;
        for (int n = 0; n < N_; n++) {
            float ar = expf(fd * sxr[n]);
            float ang = fd * sxi[n];
            float wdr = ar * cosf(ang), wdi = ar * sinf(ang);
            if (d < T_) {
                kd = fmaf(scr[n], wdr, kd);
                kd = fmaf(-sci[n], wdi, kd);
                Wv[((size_t)ih * 64 + 2 * n) * T_ + (127 - d)]     = (_Float16)wdr;
                Wv[((size_t)ih * 64 + 2 * n + 1) * T_ + (127 - d)] = (_Float16)wdi;
            }
            if (d >= 1) {
                float vr = scr[n] * wdr - sci[n] * wdi;
                float vi = scr[n] * wdi + sci[n] * wdr;
                Vt[((size_t)ih * T_ + (d - 1)) * 64 + 2 * n]     = (_Float16)vr;
                Vt[((size_t)ih * T_ + (d - 1)) * 64 + 2 * n + 1] = (_Float16)(-vi);
            }
        }
        if (d < T_) skd[d] = kd;
    }
    __syncthreads();
    if (t < T_) {
        float v = skd[127 - t];
        if (t == 127) v += Dp[ih];
        G[(size_t)ih * 256 + t]       = (_Float16)v;
        G[(size_t)ih * 256 + 128 + t] = (_Float16)0.f;
    }
}

// ---------------- fused persistent kernel: encoder -> 4x(conv2, glu) -> decoder ----------------
__global__ __launch_bounds__(256, 2) void fused_k(
    const float* __restrict__ x, const float* __restrict__ ew, const float* __restrict__ eb,
    const _Float16* __restrict__ G, const _Float16* __restrict__ Vt, const _Float16* __restrict__ Wv,
    const float* __restrict__ wtr, const float* __restrict__ wti,
    const _Float16* __restrict__ W16, const float* __restrict__ outb,
    const float* __restrict__ lnw, const float* __restrict__ lnb,
    const _Float16* __restrict__ dwp, const float* __restrict__ db,
    _Float16* __restrict__ z16, _Float16* __restrict__ y16,
    float* __restrict__ outp, int* bar)
{
    __shared__ __align__(16) char smem[73728];
    int t  = threadIdx.x;
    int lane = t & 63, wid = t >> 6;
    int l15 = lane & 15, quad = lane >> 4;
    int ph = 0;

    // ================= encoder =================
    {
        _Float16* xs  = (_Float16*)smem;                 // [128][72]
        _Float16* ews = (_Float16*)(smem + 18432);       // [256][72]
        _Float16* ot  = (_Float16*)smem;                 // [256][136]
        int vid = blockIdx.x;
        int b  = vid >> 5;
        int l0 = (vid & 31) << 7;
#pragma unroll
        for (int j = 0; j < 8; j++) {
            int idx = j * 256 + t;
            int l = idx >> 4, i4 = (idx & 15) * 4;
            float4 v = *(const float4*)(x + ((size_t)(b * L_ + l0 + l)) * DIN + i4);
            _Float16 c[4] = {(_Float16)v.x, (_Float16)v.y, (_Float16)v.z, (_Float16)v.w};
            *(uint2*)&xs[l * 72 + i4] = *(uint2*)c;
        }
#pragma unroll
        for (int j = 0; j < 16; j++) {
            int idx = j * 256 + t;
            int h = idx >> 4, i4 = (idx & 15) * 4;
            float4 v = *(const float4*)(ew + h * 64 + i4);
            _Float16 c[4] = {(_Float16)v.x, (_Float16)v.y, (_Float16)v.z, (_Float16)v.w};
            *(uint2*)&ews[h * 72 + i4] = *(uint2*)c;
        }
        __syncthreads();
        f32x4 acc[4][8];
#pragma unroll
        for (int mt = 0; mt < 4; mt++)
#pragma unroll
            for (int nt = 0; nt < 8; nt++) acc[mt][nt] = (f32x4){0.f,0.f,0.f,0.f};
#pragma unroll
        for (int ks = 0; ks < 2; ks++) {
            int kk = ks * 32 + quad * 8;
            half8 a[4], bb[8];
#pragma unroll
            for (int mt = 0; mt < 4; mt++)
                a[mt] = *(const half8*)&ews[(wid * 64 + mt * 16 + l15) * 72 + kk];
#pragma unroll
            for (int nt = 0; nt < 8; nt++)
                bb[nt] = *(const half8*)&xs[(nt * 16 + l15) * 72 + kk];
#pragma unroll
            for (int mt = 0; mt < 4; mt++)
#pragma unroll
                for (int nt = 0; nt < 8; nt++)
                    acc[mt][nt] = __builtin_amdgcn_mfma_f32_16x16x32_f16(a[mt], bb[nt], acc[mt][nt], 0, 0, 0);
        }
        __syncthreads();
#pragma unroll
        for (int mt = 0; mt < 4; mt++) {
            int hb = wid * 64 + mt * 16 + quad * 4;
            float b0 = eb[hb], b1 = eb[hb + 1], b2 = eb[hb + 2], b3 = eb[hb + 3];
#pragma unroll
            for (int nt = 0; nt < 8; nt++) {
                int l = nt * 16 + l15;
                ot[(hb + 0) * 136 + l] = (_Float16)(acc[mt][nt][0] + b0);
                ot[(hb + 1) * 136 + l] = (_Float16)(acc[mt][nt][1] + b1);
                ot[(hb + 2) * 136 + l] = (_Float16)(acc[mt][nt][2] + b2);
                ot[(hb + 3) * 136 + l] = (_Float16)(acc[mt][nt][3] + b3);
            }
        }
        __syncthreads();
#pragma unroll
        for (int p = 0; p < 16; p++) {
            int row = p * 16 + (t >> 4), seg = t & 15;
            uint4 v = *(uint4*)&ot[row * 136 + seg * 8];
            *(uint4*)(z16 + ((size_t)(b * H_ + row)) * L_ + l0 + seg * 8) = v;
        }
    }
    gbar(bar, ph++);

    // ================= layers =================
    for (int i = 0; i < NL_; i++) {
        const _Float16* Gl  = G  + (size_t)i * H_ * 256;
        const _Float16* Vtl = Vt + (size_t)i * H_ * T_ * 64;
        const _Float16* Wvl = Wv + (size_t)i * H_ * 64 * T_;
        const float* wtrl = wtr + (size_t)i * H_ * N_;
        const float* wtil = wti + (size_t)i * H_ * N_;
        const _Float16* Wl = W16 + (size_t)i * 2 * H_ * H_;
        const float* obl = outb + i * 2 * H_;
        const float* lwl = lnw + i * H_;
        const float* lbl = lnb + i * H_;

        // ---- conv2 stage: 2048 tiles, 4 iters ----
        {
            _Float16* zT = (_Float16*)smem;              // [64][136]
            _Float16* Ff = (_Float16*)(smem + 17408);    // [64][72]
            _Float16* Gs = (_Float16*)(smem + 26624);    // [256]
            for (int v2 = blockIdx.x; v2 < 2048; v2 += NBLK) {
                int h = v2 & 255, rb = v2 >> 8;
                int b0 = rb * 2;
#pragma unroll
                for (int q = 0; q < 4; q++) {
                    int idx = q * 256 + t;
                    int brow = idx >> 9;
                    int e = (idx & 511) * 8;
                    uint4 v = *(const uint4*)(z16 + ((size_t)((b0 + brow) * H_ + h)) * L_ + e);
                    int c = e >> 7, jj = e & 127;
                    *(uint4*)&zT[(brow * 32 + c) * 136 + jj] = v;
                }
                Gs[t] = Gl[(size_t)h * 256 + t];
                __syncthreads();
                {
                    int brow = wid & 1, mhalf = wid >> 1;
                    f32x4 facc[2][2];
#pragma unroll
                    for (int mt = 0; mt < 2; mt++) {
                        facc[mt][0] = (f32x4){0.f,0.f,0.f,0.f};
                        facc[mt][1] = (f32x4){0.f,0.f,0.f,0.f};
                    }
                    const _Float16* wvb = Wvl + (size_t)h * 64 * T_;
#pragma unroll
                    for (int ks = 0; ks < 4; ks++) {
                        int kk = ks * 32 + quad * 8;
                        half8 bf0 = *(const half8*)&zT[(brow * 32 + l15) * 136 + kk];
                        half8 bf1 = *(const half8*)&zT[(brow * 32 + 16 + l15) * 136 + kk];
#pragma unroll
                        for (int mt = 0; mt < 2; mt++) {
                            half8 a = *(const half8*)(wvb + (size_t)((mhalf * 2 + mt) * 16 + l15) * T_ + kk);
                            facc[mt][0] = __builtin_amdgcn_mfma_f32_16x16x32_f16(a, bf0, facc[mt][0], 0, 0, 0);
                            facc[mt][1] = __builtin_amdgcn_mfma_f32_16x16x32_f16(a, bf1, facc[mt][1], 0, 0, 0);
                        }
                    }
#pragma unroll
                    for (int mt = 0; mt < 2; mt++)
#pragma unroll
                        for (int nt = 0; nt < 2; nt++) {
                            int cr = brow * 32 + nt * 16 + l15;
                            int cc = (mhalf * 2 + mt) * 16 + quad * 4;
#pragma unroll
                            for (int r = 0; r < 4; r++)
                                Ff[cr * 72 + cc + r] = (_Float16)facc[mt][nt][r];
                        }
                }
                __syncthreads();
                if (wid < 2 && lane < 32) {
                    int n = lane;
                    float wr = wtrl[h * N_ + n], wi = wtil[h * N_ + n];
                    float cr = 0.f, ci = 0.f;
                    for (int c = 0; c < CH_; c++) {
                        float fr = (float)Ff[(wid * 32 + c) * 72 + 2 * n];
                        float fi = (float)Ff[(wid * 32 + c) * 72 + 2 * n + 1];
                        Ff[(wid * 32 + c) * 72 + 2 * n]     = (_Float16)cr;
                        Ff[(wid * 32 + c) * 72 + 2 * n + 1] = (_Float16)ci;
                        float nr = fmaf(wr, cr, fr);
                        nr = fmaf(-wi, ci, nr);
                        float ni = fmaf(wi, cr, fi);
                        ni = fmaf(wr, ci, ni);
                        cr = nr; ci = ni;
                    }
                }
                __syncthreads();
                f32x4 acc[2][4];
#pragma unroll
                for (int mt = 0; mt < 2; mt++)
#pragma unroll
                    for (int nt = 0; nt < 4; nt++) acc[mt][nt] = (f32x4){0.f,0.f,0.f,0.f};
#pragma unroll
                for (int ks = 0; ks < 4; ks++) {
                    int kk = ks * 32 + quad * 8;
                    int base0 = 127 - (wid * 32 + l15) + kk;
                    int base1 = base0 - 16;
                    half8 a0, a1;
#pragma unroll
                    for (int j = 0; j < 8; j++) { a0[j] = Gs[base0 + j]; a1[j] = Gs[base1 + j]; }
#pragma unroll
                    for (int nt = 0; nt < 4; nt++) {
                        half8 bf = *(const half8*)&zT[(nt * 16 + l15) * 136 + kk];
                        acc[0][nt] = __builtin_amdgcn_mfma_f32_16x16x32_f16(a0, bf, acc[0][nt], 0, 0, 0);
                        acc[1][nt] = __builtin_amdgcn_mfma_f32_16x16x32_f16(a1, bf, acc[1][nt], 0, 0, 0);
                    }
                }
                // FIX (R12 bug): correction Vt must be offset by h
                const _Float16* vb = Vtl + (size_t)h * T_ * 64;
#pragma unroll
                for (int ks = 0; ks < 2; ks++) {
                    int kk = ks * 32 + quad * 8;
                    half8 a0 = *(const half8*)(vb + ((size_t)(wid * 32 + l15)) * 64 + kk);
                    half8 a1 = *(const half8*)(vb + ((size_t)(wid * 32 + 16 + l15)) * 64 + kk);
#pragma unroll
                    for (int nt = 0; nt < 4; nt++) {
                        half8 bf = *(const half8*)&Ff[(nt * 16 + l15) * 72 + kk];
                        acc[0][nt] = __builtin_amdgcn_mfma_f32_16x16x32_f16(a0, bf, acc[0][nt], 0, 0, 0);
                        acc[1][nt] = __builtin_amdgcn_mfma_f32_16x16x32_f16(a1, bf, acc[1][nt], 0, 0, 0);
                    }
                }
                __syncthreads();
#pragma unroll
                for (int mt = 0; mt < 2; mt++)
#pragma unroll
                    for (int nt = 0; nt < 4; nt++) {
                        int r = nt * 16 + l15;
                        int tt0 = wid * 32 + mt * 16 + quad * 4;
                        _Float16 o[4];
#pragma unroll
                        for (int rr = 0; rr < 4; rr++) o[rr] = (_Float16)gelu_f(acc[mt][nt][rr]);
                        *(uint2*)&zT[r * 136 + tt0] = *(uint2*)o;
                    }
                __syncthreads();
#pragma unroll
                for (int q = 0; q < 4; q++) {
                    int idx = q * 256 + t;
                    int brow = idx >> 9;
                    int e = (idx & 511) * 8;
                    int c = e >> 7, jj = e & 127;
                    uint4 v = *(uint4*)&zT[(brow * 32 + c) * 136 + jj];
                    *(uint4*)(y16 + ((size_t)((b0 + brow) * H_ + h)) * L_ + e) = v;
                }
                __syncthreads();
            }
        }
        gbar(bar, ph++);

        // ---- glu stage: 1024 tiles, 2 iters ----
        {
            _Float16* yT  = (_Float16*)smem;             // [64][266] | us [256][66]
            _Float16* us  = (_Float16*)smem;
            _Float16* zs  = (_Float16*)(smem + 34048);   // [256][64]
            float* red    = (float*)(smem + 66816);      // [2][4][64]
            float* mus    = (float*)(smem + 68864);      // [64]
            float* rss    = (float*)(smem + 69120);      // [64]
            for (int v2 = blockIdx.x; v2 < 1024; v2 += NBLK) {
                int b  = v2 >> 6;
                int l0 = (v2 & 63) << 6;
                {
                    const uint4* src = (const uint4*)(y16 + ((size_t)(b * H_ + t)) * L_ + l0);
                    uint4 v[8];
#pragma unroll
                    for (int j = 0; j < 8; j++) v[j] = src[j];
                    {
                        int rsub = lane >> 3, csub = (lane & 7) * 8;
#pragma unroll
                        for (int q = 0; q < 8; q++) {
                            int ch = wid * 64 + q * 8 + rsub;
                            const _Float16* gp = z16 + ((size_t)(b * H_ + ch)) * L_ + l0 + csub;
                            __builtin_amdgcn_global_load_lds((GAS unsigned*)(const void*)gp,
                                                             (LAS unsigned*)(void*)&zs[(wid * 64 + q * 8) * 64],
                                                             16, 0, 0);
                        }
                    }
                    const _Float16* hv = (const _Float16*)v;
#pragma unroll
                    for (int j = 0; j < 64; j++) yT[j * 266 + t] = hv[j];
                }
                __syncthreads();
                f32x4 acc[8][4];
#pragma unroll
                for (int mt = 0; mt < 8; mt++)
#pragma unroll
                    for (int nt = 0; nt < 4; nt++) acc[mt][nt] = (f32x4){0.f,0.f,0.f,0.f};
#pragma unroll
                for (int ks = 0; ks < 8; ks++) {
                    int kk = ks * 32 + quad * 8;
                    half8 bf[4];
#pragma unroll
                    for (int nt = 0; nt < 4; nt++) bf[nt] = *(const half8*)&yT[(nt * 16 + l15) * 266 + kk];
#pragma unroll
                    for (int mt = 0; mt < 8; mt++) {
                        int row = (mt >> 2) * 256 + wid * 64 + (mt & 3) * 16 + l15;
                        half8 a = *(const half8*)(Wl + (size_t)row * H_ + kk);
#pragma unroll
                        for (int nt = 0; nt < 4; nt++)
                            acc[mt][nt] = __builtin_amdgcn_mfma_f32_16x16x32_f16(a, bf[nt], acc[mt][nt], 0, 0, 0);
                    }
                }
                __syncthreads();
#pragma unroll
                for (int mt = 0; mt < 4; mt++) {
                    int chb = wid * 64 + mt * 16 + quad * 4;
                    float4 ob1 = *(const float4*)(obl + chb);
                    float4 ob2 = *(const float4*)(obl + 256 + chb);
                    const float* o1 = (const float*)&ob1;
                    const float* o2 = (const float*)&ob2;
#pragma unroll
                    for (int nt = 0; nt < 4; nt++) {
                        int l = nt * 16 + l15;
#pragma unroll
                        for (int r = 0; r < 4; r++) {
                            float g1 = acc[mt][nt][r] + o1[r];
                            float g2 = acc[mt + 4][nt][r] + o2[r];
                            float sg = 1.f / (1.f + __expf(-g2));
                            us[(chb + r) * 66 + l] = (_Float16)(g1 * sg);
                        }
                    }
                }
                __syncthreads();
                {
                    int lr = t & 63, grp = t >> 6;
                    float s1 = 0.f, s2 = 0.f;
                    for (int j = 0; j < 64; j++) {
                        int ch = grp * 64 + j;
                        float uu = (float)us[ch * 66 + lr] + (float)zs[ch * 64 + lr];
                        us[ch * 66 + lr] = (_Float16)uu;
                        s1 += uu; s2 = fmaf(uu, uu, s2);
                    }
                    red[(0 * 4 + grp) * 64 + lr] = s1;
                    red[(1 * 4 + grp) * 64 + lr] = s2;
                }
                __syncthreads();
                if (t < 64) {
                    float a = red[0*256 + 0*64 + t] + red[0*256 + 1*64 + t] + red[0*256 + 2*64 + t] + red[0*256 + 3*64 + t];
                    float q = red[1*256 + 0*64 + t] + red[1*256 + 1*64 + t] + red[1*256 + 2*64 + t] + red[1*256 + 3*64 + t];
                    float mu  = a * (1.f / 256.f);
                    float var = q * (1.f / 256.f) - mu * mu;
                    mus[t] = mu; rss[t] = rsqrtf(var + 1e-5f);
                }
                __syncthreads();
                {
                    int lg = (t & 15) * 4, ch0 = t >> 4;
                    float mu4[4], rs4[4];
#pragma unroll
                    for (int i2 = 0; i2 < 4; i2++) { mu4[i2] = mus[lg + i2]; rs4[i2] = rss[lg + i2]; }
#pragma unroll
                    for (int j = 0; j < 16; j++) {
                        int ch = ch0 + 16 * j;
                        float wv = lwl[ch], bv = lbl[ch];
                        _Float16 o4[4];
#pragma unroll
                        for (int i2 = 0; i2 < 4; i2++) {
                            float vv = ((float)us[ch * 66 + lg + i2] - mu4[i2]) * rs4[i2] * wv + bv;
                            o4[i2] = (_Float16)vv;
                        }
                        *(uint2*)(z16 + ((size_t)(b * H_ + ch)) * L_ + l0 + lg) = *(uint2*)o4;
                    }
                }
                __syncthreads();
            }
        }
        gbar(bar, ph++);
    }

    // ================= decoder =================
    {
        _Float16* zT = (_Float16*)smem;                  // [128][268]
        int vid = blockIdx.x;
        int b  = vid >> 5;
        int l0 = (vid & 31) << 7;
#pragma unroll 8
        for (int j = 0; j < 64; j++) {
            int idx = j * 256 + t;
            int h = idx >> 6, lp = idx & 63;
            unsigned v = *(const unsigned*)(z16 + ((size_t)(b * H_ + h)) * L_ + l0 + lp * 2);
            union { unsigned u; _Float16 f[2]; } c; c.u = v;
            zT[(lp * 2) * 268 + h]     = c.f[0];
            zT[(lp * 2 + 1) * 268 + h] = c.f[1];
        }
        __syncthreads();
        f32x4 acc[2];
        acc[0] = (f32x4){0.f,0.f,0.f,0.f};
        acc[1] = (f32x4){0.f,0.f,0.f,0.f};
#pragma unroll
        for (int ks = 0; ks < 8; ks++) {
            int kk = ks * 32 + quad * 8;
            half8 a = *(const half8*)(dwp + l15 * 256 + kk);
#pragma unroll
            for (int nt = 0; nt < 2; nt++) {
                int l = (wid * 2 + nt) * 16 + l15;
                half4 lo = *(const half4*)&zT[l * 268 + kk];
                half4 hi = *(const half4*)&zT[l * 268 + kk + 4];
                half8 bf;
#pragma unroll
                for (int j = 0; j < 4; j++) { bf[j] = lo[j]; bf[j + 4] = hi[j]; }
                acc[nt] = __builtin_amdgcn_mfma_f32_16x16x32_f16(a, bf, acc[nt], 0, 0, 0);
            }
        }
        int o0 = quad * 4;
#pragma unroll
        for (int nt = 0; nt < 2; nt++) {
            int l = (wid * 2 + nt) * 16 + l15;
            float* op = outp + ((size_t)(b * L_ + l0 + l)) * DOUT;
#pragma unroll
            for (int r = 0; r < 4; r++) {
                int o = o0 + r;
                if (o < DOUT) op[o] = acc[nt][r] + db[o];
            }
        }
    }
}

extern "C" void kernel_launch(void* const* d_in, const int* in_sizes, int n_in,
                              void* d_out, int out_size, void* d_ws, size_t ws_size,
                              hipStream_t stream)
{
    (void)in_sizes; (void)n_in; (void)out_size; (void)ws_size;
    const float* x          = (const float*)d_in[0];
    const float* enc_w      = (const float*)d_in[1];
    const float* enc_b      = (const float*)d_in[2];
    const float* log_dt     = (const float*)d_in[3];
    const float* log_A_real = (const float*)d_in[4];
    const float* A_imag     = (const float*)d_in[5];
    const float* C_re       = (const float*)d_in[6];
    const float* C_im       = (const float*)d_in[7];
    const float* Dp         = (const float*)d_in[8];
    const float* out_w      = (const float*)d_in[9];
    const float* out_b      = (const float*)d_in[10];
    const float* ln_w       = (const float*)d_in[11];
    const float* ln_b       = (const float*)d_in[12];
    const float* dec_w      = (const float*)d_in[13];
    const float* dec_b      = (const float*)d_in[14];
    float* outp = (float*)d_out;

    char* ws = (char*)d_ws;
    _Float16* z16 = (_Float16*)ws;   ws += (size_t)B_ * H_ * L_ * 2;
    _Float16* y16 = (_Float16*)ws;   ws += (size_t)B_ * H_ * L_ * 2;
    _Float16* Wv = (_Float16*)ws;    ws += (size_t)NL_ * H_ * 64 * T_ * 2;
    _Float16* Vt = (_Float16*)ws;    ws += (size_t)NL_ * H_ * T_ * 64 * 2;
    _Float16* G  = (_Float16*)ws;    ws += (size_t)NL_ * H_ * 256 * 2;
    size_t tb = (size_t)NL_ * H_ * N_;
    float* wtr = (float*)ws; ws += tb * 4;
    float* wti = (float*)ws; ws += tb * 4;
    _Float16* W16 = (_Float16*)ws; ws += (size_t)NL_ * 2 * H_ * H_ * 2;
    _Float16* dwp = (_Float16*)ws; ws += (size_t)16 * H_ * 2;
    int* bar = (int*)ws; ws += 4096;

    hipMemsetAsync(bar, 0, 4096, stream);
    gen_k<<<NL_ * H_, 256, 0, stream>>>(log_dt, log_A_real, A_imag, C_re, C_im, Dp,
                                        Wv, Vt, G, wtr, wti, out_w, W16, dec_w, dwp);
    fused_k<<<NBLK, 256, 0, stream>>>(x, enc_w, enc_b, G, Vt, Wv, wtr, wti,
                                      W16, out_b, ln_w, ln_b, dwp, dec_b,
                                      z16, y16, outp, bar);
}

// Round 14
// 505.118 us; speedup vs baseline: 3.9813x; 3.9813x over previous
//
#include <hip/hip_runtime.h>
#include <hip/hip_fp16.h>

#define B_   16
#define L_   4096
#define DIN  64
#define H_   256
#define N_   32
#define NL_  4
#define DOUT 10
#define CH_  32
#define T_   128

typedef _Float16 half8 __attribute__((ext_vector_type(8)));
typedef _Float16 half4 __attribute__((ext_vector_type(4)));
typedef float f32x4 __attribute__((ext_vector_type(4)));

__device__ __forceinline__ float gelu_f(float v) {
    float t3  = v * v * v;
    float arg = 0.7978845608028654f * fmaf(0.044715f, t3, v);
    float e   = __expf(2.f * arg);
    float th  = 1.f - 2.f / (e + 1.f);
    return 0.5f * v * (1.f + th);
}

// ---------------- table generation: per (layer,h) block ----------------
__global__ __launch_bounds__(256) void gen_k(
    const float* __restrict__ log_dt, const float* __restrict__ log_A_real,
    const float* __restrict__ A_imag, const float* __restrict__ C_re, const float* __restrict__ C_im,
    const float* __restrict__ Dp,
    _Float16* __restrict__ Wv, _Float16* __restrict__ Vt, _Float16* __restrict__ G,
    float* __restrict__ wtr, float* __restrict__ wti)
{
    __shared__ float sxr[N_], sxi[N_], scr[N_], sci[N_], skd[T_];
    int ih = blockIdx.x;
    int t  = threadIdx.x;
    if (t < N_) {
        int n = t;
        float dt  = expf(log_dt[ih]);
        float Are = -expf(log_A_real[ih * N_ + n]);
        float Aim = A_imag[ih * N_ + n];
        float xr = dt * Are, xi = dt * Aim;
        float ex = expf(xr), cy = cosf(xi), sy = sinf(xi);
        float sh = sinf(0.5f * xi);
        float em_re = expm1f(xr) * cy - 2.f * sh * sh;
        float em_im = ex * sy;
        float inv = 1.f / (Are * Are + Aim * Aim);
        float qr = (em_re * Are + em_im * Aim) * inv;
        float qi = (em_im * Are - em_re * Aim) * inv;
        float crv = C_re[ih * N_ + n], civ = C_im[ih * N_ + n];
        sxr[n] = xr; sxi[n] = xi;
        scr[n] = 2.f * (crv * qr - civ * qi);
        sci[n] = 2.f * (crv * qi + civ * qr);
        float txr = 128.f * xr, txi = 128.f * xi;
        float exT = expf(txr);
        wtr[ih * N_ + n] = exT * cosf(txi);
        wti[ih * N_ + n] = exT * sinf(txi);
    }
    __syncthreads();
    if (t <= T_) {
        int d = t;
        float fd = (float)d;
        float kd = 0.f;
        for (int n = 0; n < N_; n++) {
            float ar = expf(fd * sxr[n]);
            float ang = fd * sxi[n];
            float wdr = ar * cosf(ang), wdi = ar * sinf(ang);
            if (d < T_) {
                kd = fmaf(scr[n], wdr, kd);
                kd = fmaf(-sci[n], wdi, kd);
                Wv[((size_t)ih * 64 + 2 * n) * T_ + (127 - d)]     = (_Float16)wdr;
                Wv[((size_t)ih * 64 + 2 * n + 1) * T_ + (127 - d)] = (_Float16)wdi;
            }
            if (d >= 1) {
                float vr = scr[n] * wdr - sci[n] * wdi;
                float vi = scr[n] * wdi + sci[n] * wdr;
                Vt[((size_t)ih * T_ + (d - 1)) * 64 + 2 * n]     = (_Float16)vr;
                Vt[((size_t)ih * T_ + (d - 1)) * 64 + 2 * n + 1] = (_Float16)(-vi);
            }
        }
        if (d < T_) skd[d] = kd;
    }
    __syncthreads();
    if (t < T_) {
        float v = skd[127 - t];
        if (t == 127) v += Dp[ih];
        G[(size_t)ih * 256 + t]       = (_Float16)v;
        G[(size_t)ih * 256 + 128 + t] = (_Float16)0.f;
    }
}

__global__ __launch_bounds__(256) void wconv_k(const float* __restrict__ w, _Float16* __restrict__ w16)
{
    int idx = blockIdx.x * 256 + threadIdx.x;
    w16[idx] = (_Float16)w[idx];
}

// decoder weight prep: 16x256 f16, rows >= DOUT zeroed
__global__ __launch_bounds__(256) void dprep_k(const float* __restrict__ dw, _Float16* __restrict__ dwp)
{
    int t = threadIdx.x;
#pragma unroll
    for (int j = 0; j < 16; j++) {
        int idx = j * 256 + t;
        dwp[idx] = (idx < DOUT * H_) ? (_Float16)dw[idx] : (_Float16)0.f;
    }
}

// ---------------- encoder: MFMA GEMM, M=256(h) x N=128(l) x K=64 ----------------
__global__ __launch_bounds__(256) void encoder_k(
    const float* __restrict__ x, const float* __restrict__ ew,
    const float* __restrict__ eb, _Float16* __restrict__ z16)
{
    __shared__ _Float16 smem[35840];      // 71680 B: xs[128][72]+ews[256][72] | ot[256][136]
    _Float16* xs  = smem;
    _Float16* ews = smem + 128 * 72;
    _Float16* ot  = smem;
    int b  = blockIdx.y;
    int l0 = blockIdx.x << 7;
    int t  = threadIdx.x;
#pragma unroll
    for (int j = 0; j < 8; j++) {
        int idx = j * 256 + t;
        int l = idx >> 4, i4 = (idx & 15) * 4;
        float4 v = *(const float4*)(x + ((size_t)(b * L_ + l0 + l)) * DIN + i4);
        _Float16 c[4] = {(_Float16)v.x, (_Float16)v.y, (_Float16)v.z, (_Float16)v.w};
        *(uint2*)&xs[l * 72 + i4] = *(uint2*)c;
    }
#pragma unroll
    for (int j = 0; j < 16; j++) {
        int idx = j * 256 + t;
        int h = idx >> 4, i4 = (idx & 15) * 4;
        float4 v = *(const float4*)(ew + h * 64 + i4);
        _Float16 c[4] = {(_Float16)v.x, (_Float16)v.y, (_Float16)v.z, (_Float16)v.w};
        *(uint2*)&ews[h * 72 + i4] = *(uint2*)c;
    }
    __syncthreads();
    int lane = t & 63, wid = t >> 6;
    int l15 = lane & 15, quad = lane >> 4;
    f32x4 acc[4][8];
#pragma unroll
    for (int mt = 0; mt < 4; mt++)
#pragma unroll
        for (int nt = 0; nt < 8; nt++) acc[mt][nt] = (f32x4){0.f,0.f,0.f,0.f};
#pragma unroll
    for (int ks = 0; ks < 2; ks++) {
        int kk = ks * 32 + quad * 8;
        half8 a[4], bb[8];
#pragma unroll
        for (int mt = 0; mt < 4; mt++)
            a[mt] = *(const half8*)&ews[(wid * 64 + mt * 16 + l15) * 72 + kk];
#pragma unroll
        for (int nt = 0; nt < 8; nt++)
            bb[nt] = *(const half8*)&xs[(nt * 16 + l15) * 72 + kk];
#pragma unroll
        for (int mt = 0; mt < 4; mt++)
#pragma unroll
            for (int nt = 0; nt < 8; nt++)
                acc[mt][nt] = __builtin_amdgcn_mfma_f32_16x16x32_f16(a[mt], bb[nt], acc[mt][nt], 0, 0, 0);
    }
    __syncthreads();
#pragma unroll
    for (int mt = 0; mt < 4; mt++) {
        int hb = wid * 64 + mt * 16 + quad * 4;
        float b0 = eb[hb], b1 = eb[hb + 1], b2 = eb[hb + 2], b3 = eb[hb + 3];
#pragma unroll
        for (int nt = 0; nt < 8; nt++) {
            int l = nt * 16 + l15;
            ot[(hb + 0) * 136 + l] = (_Float16)(acc[mt][nt][0] + b0);
            ot[(hb + 1) * 136 + l] = (_Float16)(acc[mt][nt][1] + b1);
            ot[(hb + 2) * 136 + l] = (_Float16)(acc[mt][nt][2] + b2);
            ot[(hb + 3) * 136 + l] = (_Float16)(acc[mt][nt][3] + b3);
        }
    }
    __syncthreads();
#pragma unroll
    for (int p = 0; p < 16; p++) {
        int row = p * 16 + (t >> 4), seg = t & 15;
        uint4 v = *(uint4*)&ot[row * 136 + seg * 8];
        *(uint4*)(z16 + ((size_t)(b * H_ + row)) * L_ + l0 + seg * 8) = v;
    }
}

// ---------------- conv2: fused finals + chunk-prefix + conv GEMM -> y16 (R10 verbatim) ----------------
__global__ __launch_bounds__(256, 3) void conv2_k(
    const _Float16* __restrict__ z16, const _Float16* __restrict__ G,
    const _Float16* __restrict__ Vt, const _Float16* __restrict__ Wv,
    const float* __restrict__ wtr, const float* __restrict__ wti,
    _Float16* __restrict__ y16)
{
    __shared__ _Float16 zT[128][136];   // 34816 B
    __shared__ _Float16 Ff[128][72];    // 18432 B
    __shared__ _Float16 Gs[256];
    int h = blockIdx.x, rb = blockIdx.y;
    int t = threadIdx.x;
    int b0 = rb * 4;
#pragma unroll
    for (int q = 0; q < 8; q++) {
        int idx = q * 256 + t;
        int brow = idx >> 9;
        int e = (idx & 511) * 8;
        uint4 v = *(const uint4*)(z16 + ((size_t)((b0 + brow) * H_ + h)) * L_ + e);
        int c = e >> 7, jj = e & 127;
        *(uint4*)&zT[brow * 32 + c][jj] = v;
    }
    Gs[t] = G[(size_t)h * 256 + t];
    __syncthreads();
    int lane = t & 63, w = t >> 6;
    int l15 = lane & 15, quad = lane >> 4;
    // ---- finals GEMM: wave w -> b-row w ----
    {
        f32x4 facc[4][2];
#pragma unroll
        for (int mt = 0; mt < 4; mt++) {
            facc[mt][0] = (f32x4){0.f,0.f,0.f,0.f};
            facc[mt][1] = (f32x4){0.f,0.f,0.f,0.f};
        }
        const _Float16* wvb = Wv + (size_t)h * 64 * T_;
#pragma unroll
        for (int ks = 0; ks < 4; ks++) {
            int kk = ks * 32 + quad * 8;
            half8 bf0 = *(const half8*)&zT[w * 32 + l15][kk];
            half8 bf1 = *(const half8*)&zT[w * 32 + 16 + l15][kk];
#pragma unroll
            for (int mt = 0; mt < 4; mt++) {
                half8 a = *(const half8*)(wvb + (size_t)(mt * 16 + l15) * T_ + kk);
                facc[mt][0] = __builtin_amdgcn_mfma_f32_16x16x32_f16(a, bf0, facc[mt][0], 0, 0, 0);
                facc[mt][1] = __builtin_amdgcn_mfma_f32_16x16x32_f16(a, bf1, facc[mt][1], 0, 0, 0);
            }
        }
#pragma unroll
        for (int mt = 0; mt < 4; mt++)
#pragma unroll
            for (int nt = 0; nt < 2; nt++) {
                int cr = w * 32 + nt * 16 + l15;
                int cc = mt * 16 + quad * 4;
#pragma unroll
                for (int r = 0; r < 4; r++)
                    Ff[cr][cc + r] = (_Float16)facc[mt][nt][r];
            }
    }
    __syncthreads();
    // ---- chunk-prefix: lane n of wave w (lanes 0..31) ----
    if (lane < 32) {
        int n = lane;
        float wr = wtr[h * N_ + n], wi = wti[h * N_ + n];
        float cr = 0.f, ci = 0.f;
        for (int c = 0; c < CH_; c++) {
            float fr = (float)Ff[w * 32 + c][2 * n];
            float fi = (float)Ff[w * 32 + c][2 * n + 1];
            Ff[w * 32 + c][2 * n]     = (_Float16)cr;
            Ff[w * 32 + c][2 * n + 1] = (_Float16)ci;
            float nr = fmaf(wr, cr, fr);
            nr = fmaf(-wi, ci, nr);
            float ni = fmaf(wi, cr, fi);
            ni = fmaf(wr, ci, ni);
            cr = nr; ci = ni;
        }
    }
    __syncthreads();
    // ---- main conv + correction ----
    f32x4 acc[2][8];
#pragma unroll
    for (int mt = 0; mt < 2; mt++)
#pragma unroll
        for (int nt = 0; nt < 8; nt++) acc[mt][nt] = (f32x4){0.f,0.f,0.f,0.f};
#pragma unroll
    for (int ks = 0; ks < 4; ks++) {
        int kk = ks * 32 + quad * 8;
        int base0 = 127 - (w * 32 + l15) + kk;
        int base1 = base0 - 16;
        half8 a0, a1;
#pragma unroll
        for (int j = 0; j < 8; j++) { a0[j] = Gs[base0 + j]; a1[j] = Gs[base1 + j]; }
#pragma unroll
        for (int nt = 0; nt < 8; nt++) {
            half8 bf = *(const half8*)&zT[nt * 16 + l15][kk];
            acc[0][nt] = __builtin_amdgcn_mfma_f32_16x16x32_f16(a0, bf, acc[0][nt], 0, 0, 0);
            acc[1][nt] = __builtin_amdgcn_mfma_f32_16x16x32_f16(a1, bf, acc[1][nt], 0, 0, 0);
        }
    }
    const _Float16* vb = Vt + (size_t)h * T_ * 64;
#pragma unroll
    for (int ks = 0; ks < 2; ks++) {
        int kk = ks * 32 + quad * 8;
        half8 a0 = *(const half8*)(vb + ((size_t)(w * 32 + l15)) * 64 + kk);
        half8 a1 = *(const half8*)(vb + ((size_t)(w * 32 + 16 + l15)) * 64 + kk);
#pragma unroll
        for (int nt = 0; nt < 8; nt++) {
            half8 bf = *(const half8*)&Ff[nt * 16 + l15][kk];
            acc[0][nt] = __builtin_amdgcn_mfma_f32_16x16x32_f16(a0, bf, acc[0][nt], 0, 0, 0);
            acc[1][nt] = __builtin_amdgcn_mfma_f32_16x16x32_f16(a1, bf, acc[1][nt], 0, 0, 0);
        }
    }
    __syncthreads();
#pragma unroll
    for (int mt = 0; mt < 2; mt++)
#pragma unroll
        for (int nt = 0; nt < 8; nt++) {
            int r = nt * 16 + l15;
            int tt0 = w * 32 + mt * 16 + quad * 4;
            _Float16 o[4];
#pragma unroll
            for (int rr = 0; rr < 4; rr++) o[rr] = (_Float16)gelu_f(acc[mt][nt][rr]);
            *(uint2*)&zT[r][tt0] = *(uint2*)o;
        }
    __syncthreads();
#pragma unroll
    for (int q = 0; q < 8; q++) {
        int idx = q * 256 + t;
        int brow = idx >> 9;
        int e = (idx & 511) * 8;
        int c = e >> 7, jj = e & 127;
        uint4 v = *(uint4*)&zT[brow * 32 + c][jj];
        *(uint4*)(y16 + ((size_t)((b0 + brow) * H_ + h)) * L_ + e) = v;
    }
}

// ---------------- GLU GEMM (M=512, N=64) + residual + LN (R5 variant — measured fastest) ----------------
__global__ __launch_bounds__(256, 2) void glu_k(
    const _Float16* __restrict__ W, const _Float16* __restrict__ y16,
    const float* __restrict__ outb, const float* __restrict__ lnw,
    const float* __restrict__ lnb, _Float16* __restrict__ z16)
{
    __shared__ float u_s[256 * 66];
    __shared__ float red[2][4][64];
    __shared__ float mus[64], rss[64];
    _Float16* yT = (_Float16*)u_s;
    int b  = blockIdx.y;
    int l0 = blockIdx.x << 6;
    int t  = threadIdx.x;
    int lane = t & 63, wid = t >> 6;
    int l15 = lane & 15, quad = lane >> 4;
    {
        const uint4* src = (const uint4*)(y16 + ((size_t)(b * H_ + t)) * L_ + l0);
        uint4 v[8];
#pragma unroll
        for (int j = 0; j < 8; j++) v[j] = src[j];
        const _Float16* hv = (const _Float16*)v;
#pragma unroll
        for (int j = 0; j < 64; j++) yT[j * 264 + t] = hv[j];
    }
    __syncthreads();
    f32x4 acc[8][4];
#pragma unroll
    for (int mt = 0; mt < 8; mt++)
#pragma unroll
        for (int nt = 0; nt < 4; nt++) acc[mt][nt] = (f32x4){0.f,0.f,0.f,0.f};
#pragma unroll
    for (int ks = 0; ks < 8; ks++) {
        int kk = ks * 32 + quad * 8;
        half8 bf[4];
#pragma unroll
        for (int nt = 0; nt < 4; nt++) bf[nt] = *(const half8*)&yT[(nt * 16 + l15) * 264 + kk];
#pragma unroll
        for (int mt = 0; mt < 8; mt++) {
            int row = (mt >> 2) * 256 + wid * 64 + (mt & 3) * 16 + l15;
            half8 a = *(const half8*)(W + (size_t)row * H_ + kk);
#pragma unroll
            for (int nt = 0; nt < 4; nt++)
                acc[mt][nt] = __builtin_amdgcn_mfma_f32_16x16x32_f16(a, bf[nt], acc[mt][nt], 0, 0, 0);
        }
    }
    __syncthreads();
#pragma unroll
    for (int mt = 0; mt < 4; mt++) {
        int chb = wid * 64 + mt * 16 + quad * 4;
        float4 ob1 = *(const float4*)(outb + chb);
        float4 ob2 = *(const float4*)(outb + 256 + chb);
        const float* o1 = (const float*)&ob1;
        const float* o2 = (const float*)&ob2;
#pragma unroll
        for (int nt = 0; nt < 4; nt++) {
            int l = nt * 16 + l15;
#pragma unroll
            for (int r = 0; r < 4; r++) {
                float g1 = acc[mt][nt][r] + o1[r];
                float g2 = acc[mt + 4][nt][r] + o2[r];
                float sg = 1.f / (1.f + __expf(-g2));
                u_s[(chb + r) * 66 + l] = g1 * sg;
            }
        }
    }
    __syncthreads();
    int lr = t & 63, grp = t >> 6;
    float s1 = 0.f, s2 = 0.f;
    for (int j = 0; j < 64; j++) {
        int ch = grp * 64 + j;
        float uu = u_s[ch * 66 + lr] + (float)z16[((size_t)(b * H_ + ch)) * L_ + l0 + lr];
        u_s[ch * 66 + lr] = uu;
        s1 += uu; s2 = fmaf(uu, uu, s2);
    }
    red[0][grp][lr] = s1; red[1][grp][lr] = s2;
    __syncthreads();
    if (t < 64) {
        float a = red[0][0][t] + red[0][1][t] + red[0][2][t] + red[0][3][t];
        float q = red[1][0][t] + red[1][1][t] + red[1][2][t] + red[1][3][t];
        float mu  = a * (1.f / 256.f);
        float var = q * (1.f / 256.f) - mu * mu;
        mus[t] = mu; rss[t] = rsqrtf(var + 1e-5f);
    }
    __syncthreads();
    int lg = (t & 15) * 4, ch0 = t >> 4;
    float mu4[4], rs4[4];
#pragma unroll
    for (int i = 0; i < 4; i++) { mu4[i] = mus[lg + i]; rs4[i] = rss[lg + i]; }
#pragma unroll
    for (int j = 0; j < 16; j++) {
        int ch = ch0 + 16 * j;
        float wv = lnw[ch], bv = lnb[ch];
        _Float16 o4[4];
#pragma unroll
        for (int i = 0; i < 4; i++) {
            float vv = (u_s[ch * 66 + lg + i] - mu4[i]) * rs4[i] * wv + bv;
            o4[i] = (_Float16)vv;
        }
        *(uint2*)(z16 + ((size_t)(b * H_ + ch)) * L_ + l0 + lg) = *(uint2*)o4;
    }
}

// ---------------- decoder: MFMA, m=o(16 padded), n=l, k=h=256 ----------------
__global__ __launch_bounds__(256) void decoder_k(
    const _Float16* __restrict__ z16, const _Float16* __restrict__ dwp,
    const float* __restrict__ db, float* __restrict__ out)
{
    __shared__ _Float16 zT[128][268];
    int b  = blockIdx.y;
    int l0 = blockIdx.x << 7;
    int t  = threadIdx.x;
#pragma unroll 8
    for (int j = 0; j < 64; j++) {
        int idx = j * 256 + t;
        int h = idx >> 6, lp = idx & 63;
        unsigned v = *(const unsigned*)(z16 + ((size_t)(b * H_ + h)) * L_ + l0 + lp * 2);
        union { unsigned u; _Float16 f[2]; } c; c.u = v;
        zT[lp * 2][h]     = c.f[0];
        zT[lp * 2 + 1][h] = c.f[1];
    }
    __syncthreads();
    int lane = t & 63, wid = t >> 6;
    int l15 = lane & 15, quad = lane >> 4;
    f32x4 acc[2];
    acc[0] = (f32x4){0.f,0.f,0.f,0.f};
    acc[1] = (f32x4){0.f,0.f,0.f,0.f};
#pragma unroll
    for (int ks = 0; ks < 8; ks++) {
        int kk = ks * 32 + quad * 8;
        half8 a = *(const half8*)(dwp + l15 * 256 + kk);
#pragma unroll
        for (int nt = 0; nt < 2; nt++) {
            int l = (wid * 2 + nt) * 16 + l15;
            half4 lo = *(const half4*)&zT[l][kk];
            half4 hi = *(const half4*)&zT[l][kk + 4];
            half8 bf;
#pragma unroll
            for (int j = 0; j < 4; j++) { bf[j] = lo[j]; bf[j + 4] = hi[j]; }
            acc[nt] = __builtin_amdgcn_mfma_f32_16x16x32_f16(a, bf, acc[nt], 0, 0, 0);
        }
    }
    int o0 = quad * 4;
#pragma unroll
    for (int nt = 0; nt < 2; nt++) {
        int l = (wid * 2 + nt) * 16 + l15;
        float* op = out + ((size_t)(b * L_ + l0 + l)) * DOUT;
#pragma unroll
        for (int r = 0; r < 4; r++) {
            int o = o0 + r;
            if (o < DOUT) op[o] = acc[nt][r] + db[o];
        }
    }
}

extern "C" void kernel_launch(void* const* d_in, const int* in_sizes, int n_in,
                              void* d_out, int out_size, void* d_ws, size_t ws_size,
                              hipStream_t stream)
{
    (void)in_sizes; (void)n_in; (void)out_size; (void)ws_size;
    const float* x          = (const float*)d_in[0];
    const float* enc_w      = (const float*)d_in[1];
    const float* enc_b      = (const float*)d_in[2];
    const float* log_dt     = (const float*)d_in[3];
    const float* log_A_real = (const float*)d_in[4];
    const float* A_imag     = (const float*)d_in[5];
    const float* C_re       = (const float*)d_in[6];
    const float* C_im       = (const float*)d_in[7];
    const float* Dp         = (const float*)d_in[8];
    const float* out_w      = (const float*)d_in[9];
    const float* out_b      = (const float*)d_in[10];
    const float* ln_w       = (const float*)d_in[11];
    const float* ln_b       = (const float*)d_in[12];
    const float* dec_w      = (const float*)d_in[13];
    const float* dec_b      = (const float*)d_in[14];
    float* outp = (float*)d_out;

    char* ws = (char*)d_ws;
    _Float16* z16 = (_Float16*)ws;   ws += (size_t)B_ * H_ * L_ * 2;
    _Float16* y16 = (_Float16*)ws;   ws += (size_t)B_ * H_ * L_ * 2;
    _Float16* Wv = (_Float16*)ws;    ws += (size_t)NL_ * H_ * 64 * T_ * 2;
    _Float16* Vt = (_Float16*)ws;    ws += (size_t)NL_ * H_ * T_ * 64 * 2;
    _Float16* G  = (_Float16*)ws;    ws += (size_t)NL_ * H_ * 256 * 2;
    size_t tb = (size_t)NL_ * H_ * N_;
    float* wtr = (float*)ws; ws += tb * 4;
    float* wti = (float*)ws; ws += tb * 4;
    _Float16* W16 = (_Float16*)ws; ws += (size_t)NL_ * 2 * H_ * H_ * 2;
    _Float16* dwp = (_Float16*)ws; ws += (size_t)16 * H_ * 2;

    gen_k<<<NL_ * H_, 256, 0, stream>>>(log_dt, log_A_real, A_imag, C_re, C_im, Dp,
                                        Wv, Vt, G, wtr, wti);
    wconv_k<<<(NL_ * 2 * H_ * H_) / 256, 256, 0, stream>>>(out_w, W16);
    dprep_k<<<1, 256, 0, stream>>>(dec_w, dwp);
    encoder_k<<<dim3(L_ / 128, B_), 256, 0, stream>>>(x, enc_w, enc_b, z16);
    for (int i = 0; i < NL_; i++) {
        size_t th = (size_t)i * H_;
        conv2_k<<<dim3(H_, B_ / 4), 256, 0, stream>>>(z16, G + th * 256, Vt + th * T_ * 64,
                                                      Wv + th * 64 * T_, wtr + th * N_, wti + th * N_,
                                                      y16);
        glu_k<<<dim3(L_ / 64, B_), 256, 0, stream>>>(W16 + (size_t)i * 2 * H_ * H_, y16,
                                                     out_b + i * 2 * H_, ln_w + th, ln_b + th, z16);
    }
    decoder_k<<<dim3(L_ / 128, B_), 256, 0, stream>>>(z16, dwp, dec_b, outp);
}